// Round 1
// baseline (1244.189 us; speedup 1.0000x reference)
//
#include <hip/hip_runtime.h>
#include <hip/hip_bf16.h>

#define N_NODES 50000
#define N_EDGES 800000
#define DD 96
#define NLAYER 4
#define N_GRAPHS 256
#define BN_EPS 1e-5f

// ---------------- workspace layout (units: 4-byte elements) ----------------
// zeroed-at-start region first (one memset covers cnt/stats/pool/gcnt):
enum : size_t {
  O_CNT    = 0,                        // int[N_NODES]  (edge-in counts, later fill cursors)
  O_STATS  = O_CNT + N_NODES,          // float[4*192]  (sum, sumsq per layer)
  O_POOL   = O_STATS + 4 * 192,        // float[N_GRAPHS*96]
  O_GCNT   = O_POOL + N_GRAPHS * DD,   // int[N_GRAPHS]
  ZERO_END = O_GCNT + N_GRAPHS,
  O_ROWPTR = ZERO_END,                 // int[N_NODES+1]
  O_DIS    = O_ROWPTR + N_NODES + 1,   // float[N_NODES]
  O_BSUMS  = O_DIS + N_NODES,          // int[256]
  O_CSRC   = O_BSUMS + 256,            // int[N_EDGES]
  O_CSRW   = O_CSRC + N_EDGES,         // float[N_EDGES]
  O_PARAMS = O_CSRW + N_EDGES,         // float[4*192]  (a, c per layer)
  O_B_RAW  = O_PARAMS + 4 * 192,
  O_B      = (O_B_RAW + 3) & ~size_t(3),  // float[N_NODES*96]  hw buffer (16B aligned)
  O_P      = O_B + N_NODES * DD,          // float[N_NODES*96]  act/agg buffer
  WS_ELEMS = O_P + N_NODES * DD           // ~45.5 MB
};

// ---------------- CSR build ----------------
__global__ void k_count(const int* __restrict__ dst, int* __restrict__ cnt) {
  int e = blockIdx.x * blockDim.x + threadIdx.x;
  if (e < N_EDGES) atomicAdd(&cnt[dst[e]], 1);
}

__global__ void k_dis(const int* __restrict__ cnt, float* __restrict__ dis) {
  int n = blockIdx.x * blockDim.x + threadIdx.x;
  if (n < N_NODES) dis[n] = rsqrtf((float)(cnt[n] + 1));  // +1 self loop; deg>=1 always
}

__global__ void k_partials(const int* __restrict__ cnt, int* __restrict__ bsums) {
  __shared__ int s[256];
  int i = blockIdx.x * 256 + threadIdx.x;
  s[threadIdx.x] = (i < N_NODES) ? cnt[i] : 0;
  __syncthreads();
  for (int off = 128; off > 0; off >>= 1) {
    if (threadIdx.x < off) s[threadIdx.x] += s[threadIdx.x + off];
    __syncthreads();
  }
  if (threadIdx.x == 0) bsums[blockIdx.x] = s[0];
}

__global__ void k_scan_bsums(int* __restrict__ bsums, int nb, int* __restrict__ rowptr) {
  if (threadIdx.x == 0 && blockIdx.x == 0) {
    int run = 0;
    for (int b = 0; b < nb; ++b) { int t = bsums[b]; bsums[b] = run; run += t; }
    rowptr[N_NODES] = run;
  }
}

__global__ void k_scan_write(const int* __restrict__ cnt, const int* __restrict__ bsums,
                             int* __restrict__ rowptr) {
  __shared__ int s[256];
  int i = blockIdx.x * 256 + threadIdx.x;
  int v = (i < N_NODES) ? cnt[i] : 0;
  s[threadIdx.x] = v;
  __syncthreads();
  for (int off = 1; off < 256; off <<= 1) {
    int x = 0;
    if (threadIdx.x >= off) x = s[threadIdx.x - off];
    __syncthreads();
    s[threadIdx.x] += x;
    __syncthreads();
  }
  if (i < N_NODES) rowptr[i] = bsums[blockIdx.x] + s[threadIdx.x] - v;  // exclusive
}

__global__ void k_fill(const int* __restrict__ ei, const int* __restrict__ rowptr,
                       int* __restrict__ cursor, const float* __restrict__ dis,
                       int* __restrict__ csrc, float* __restrict__ csrw) {
  int e = blockIdx.x * blockDim.x + threadIdx.x;
  if (e >= N_EDGES) return;
  int s = ei[e];            // src row
  int d = ei[N_EDGES + e];  // dst row
  int pos = rowptr[d] + atomicAdd(&cursor[d], 1);
  csrc[pos] = s;
  csrw[pos] = dis[s] * dis[d];
}

// ---------------- GEMM: Y[r][f] = act(X[r][:]) @ W, act = BN+ReLU of prev layer ----------------
// block: 192 threads = 24 feature-groups(x4) * 8 row-groups; 48 rows per block
__global__ __launch_bounds__(192) void k_gemm(const float* __restrict__ X,
                                              const float* __restrict__ Wg,
                                              const float* __restrict__ prm,
                                              float* __restrict__ Y) {
  __shared__ float Ws[96 * 96];
  __shared__ float Hs[48][100];  // +4 pad breaks stride-96 bank aliasing
  __shared__ float sA[96], sC[96];
  const int tid = threadIdx.x;
  const int fg = tid % 24;
  const int rg = tid / 24;
  const int row0 = blockIdx.x * 48;

  for (int i = tid; i < 96 * 96; i += 192) Ws[i] = Wg[i];
  if (tid < 96) {
    if (prm) { sA[tid] = prm[tid]; sC[tid] = prm[96 + tid]; }
    else     { sA[tid] = 1.f;      sC[tid] = 0.f; }
  }
  __syncthreads();
  const bool bn = (prm != nullptr);
  for (int i = tid; i < 48 * 96; i += 192) {
    int r = i / 96, c = i - r * 96;
    int gr = row0 + r;
    float v = (gr < N_NODES) ? X[gr * 96 + c] : 0.f;
    if (bn) v = fmaxf(v * sA[c] + sC[c], 0.f);
    Hs[r][c] = v;
  }
  __syncthreads();

  float4 acc[6];
#pragma unroll
  for (int j = 0; j < 6; ++j) acc[j] = make_float4(0.f, 0.f, 0.f, 0.f);
  const int f4 = fg * 4;
  for (int k4 = 0; k4 < 96; k4 += 4) {
    float4 w0 = *(const float4*)&Ws[(k4 + 0) * 96 + f4];
    float4 w1 = *(const float4*)&Ws[(k4 + 1) * 96 + f4];
    float4 w2 = *(const float4*)&Ws[(k4 + 2) * 96 + f4];
    float4 w3 = *(const float4*)&Ws[(k4 + 3) * 96 + f4];
#pragma unroll
    for (int j = 0; j < 6; ++j) {
      const float4 h = *(const float4*)&Hs[rg + j * 8][k4];
      acc[j].x += h.x * w0.x + h.y * w1.x + h.z * w2.x + h.w * w3.x;
      acc[j].y += h.x * w0.y + h.y * w1.y + h.z * w2.y + h.w * w3.y;
      acc[j].z += h.x * w0.z + h.y * w1.z + h.z * w2.z + h.w * w3.z;
      acc[j].w += h.x * w0.w + h.y * w1.w + h.z * w2.w + h.w * w3.w;
    }
  }
#pragma unroll
  for (int j = 0; j < 6; ++j) {
    int r = row0 + rg + j * 8;
    if (r < N_NODES) *(float4*)&Y[r * 96 + f4] = acc[j];
  }
}

// ---------------- aggregation: agg[n][f] = sum_j w_j * hw[src_j][f] + hw[n][f]*dis[n]^2 ----------------
__global__ void k_gather(const float* __restrict__ hw, const int* __restrict__ rowptr,
                         const int* __restrict__ csrc, const float* __restrict__ csrw,
                         const float* __restrict__ dis, float* __restrict__ agg) {
  int t = blockIdx.x * blockDim.x + threadIdx.x;
  if (t >= N_NODES * DD) return;
  int n = t / 96;
  int f = t - n * 96;
  float dn = dis[n];
  float acc = hw[t] * (dn * dn);  // self loop: norm = dis[n]*dis[n]
  int s = rowptr[n], e = rowptr[n + 1];
  for (int j = s; j < e; ++j) {
    acc = fmaf(csrw[j], hw[csrc[j] * 96 + f], acc);
  }
  agg[t] = acc;
}

// ---------------- BN stats: per-channel sum & sumsq ----------------
__global__ __launch_bounds__(192) void k_stats(const float* __restrict__ agg,
                                               float* __restrict__ stats) {
  int f = threadIdx.x % 96;
  int half = threadIdx.x / 96;
  int r0 = blockIdx.x * 512;
  int r1 = min(r0 + 512, N_NODES);
  float s = 0.f, s2 = 0.f;
  for (int r = r0 + half; r < r1; r += 2) {
    float v = agg[r * 96 + f];
    s += v;
    s2 += v * v;
  }
  atomicAdd(&stats[f], s);
  atomicAdd(&stats[96 + f], s2);
}

__global__ void k_bnparams(const float* __restrict__ stats, const float* __restrict__ gamma,
                           const float* __restrict__ beta, float* __restrict__ prm) {
  int f = threadIdx.x;
  if (f >= 96) return;
  float mu = stats[f] * (1.f / N_NODES);
  float var = stats[96 + f] * (1.f / N_NODES) - mu * mu;
  var = fmaxf(var, 0.f);
  float a = gamma[f] * rsqrtf(var + BN_EPS);
  prm[f] = a;             // scale
  prm[96 + f] = beta[f] - mu * a;  // shift (bias b cancels through BN -> ignored)
}

// ---------------- pooling (applies final BN+ReLU on the fly; batch is sorted) ----------------
__global__ void k_pool(const float* __restrict__ h, const float* __restrict__ prm,
                       const int* __restrict__ batch, float* __restrict__ pool) {
  int f = threadIdx.x;  // 96
  int start = blockIdx.x * 256;
  int end = min(start + 256, N_NODES);
  float A = prm[f], C = prm[96 + f];
  int cur = batch[start];
  float acc = 0.f;
  for (int n = start; n < end; ++n) {
    int g = batch[n];
    if (g != cur) {
      atomicAdd(&pool[cur * 96 + f], acc);
      acc = 0.f;
      cur = g;
    }
    acc += fmaxf(h[n * 96 + f] * A + C, 0.f);
  }
  atomicAdd(&pool[cur * 96 + f], acc);
}

__global__ void k_gcount(const int* __restrict__ batch, int* __restrict__ gcnt) {
  int n = blockIdx.x * blockDim.x + threadIdx.x;
  if (n < N_NODES) atomicAdd(&gcnt[batch[n]], 1);
}

__global__ void k_out(const float* __restrict__ pool, const int* __restrict__ gcnt,
                      float* __restrict__ out) {
  int t = blockIdx.x * blockDim.x + threadIdx.x;
  if (t >= N_GRAPHS * 96) return;
  int g = t / 96;
  int c = gcnt[g];
  if (c < 1) c = 1;
  out[t] = pool[t] / (float)c;
}

extern "C" void kernel_launch(void* const* d_in, const int* in_sizes, int n_in,
                              void* d_out, int out_size, void* d_ws, size_t ws_size,
                              hipStream_t stream) {
  const float* x     = (const float*)d_in[0];
  const int*   ei    = (const int*)d_in[1];   // [2, E] row-major: src then dst
  const int*   batch = (const int*)d_in[2];
  const float* W     = (const float*)d_in[3]; // [4,96,96]
  // d_in[4] = b : cancels exactly through BatchNorm, unused
  const float* gamma = (const float*)d_in[5]; // [4,96]
  const float* beta  = (const float*)d_in[6];
  float* out = (float*)d_out;

  float* ws = (float*)d_ws;
  int*   cnt    = (int*)(ws + O_CNT);
  float* stats  = ws + O_STATS;
  float* pool   = ws + O_POOL;
  int*   gcnt   = (int*)(ws + O_GCNT);
  int*   rowptr = (int*)(ws + O_ROWPTR);
  float* dis    = ws + O_DIS;
  int*   bsums  = (int*)(ws + O_BSUMS);
  int*   csrc   = (int*)(ws + O_CSRC);
  float* csrw   = ws + O_CSRW;
  float* prm    = ws + O_PARAMS;
  float* B      = ws + O_B;  // hw
  float* P      = ws + O_P;  // act / agg

  hipMemsetAsync(d_ws, 0, ZERO_END * sizeof(float), stream);

  const int eb = (N_EDGES + 255) / 256;
  const int nb = (N_NODES + 255) / 256;  // 196
  k_count<<<eb, 256, 0, stream>>>(ei + N_EDGES, cnt);
  k_dis<<<nb, 256, 0, stream>>>(cnt, dis);
  k_partials<<<nb, 256, 0, stream>>>(cnt, bsums);
  k_scan_bsums<<<1, 64, 0, stream>>>(bsums, nb, rowptr);
  k_scan_write<<<nb, 256, 0, stream>>>(cnt, bsums, rowptr);
  hipMemsetAsync(cnt, 0, N_NODES * sizeof(int), stream);  // reuse as fill cursors
  k_fill<<<eb, 256, 0, stream>>>(ei, rowptr, cnt, dis, csrc, csrw);

  const int gemmb = (N_NODES + 47) / 48;          // 1042
  const int gatherb = (N_NODES * DD + 255) / 256; // 18750
  const int statsb = (N_NODES + 511) / 512;       // 98

  const float* hin = x;
  for (int l = 0; l < NLAYER; ++l) {
    const float* pin = (l == 0) ? nullptr : (prm + (l - 1) * 192);
    k_gemm<<<gemmb, 192, 0, stream>>>(hin, W + l * 96 * 96, pin, B);
    k_gather<<<gatherb, 256, 0, stream>>>(B, rowptr, csrc, csrw, dis, P);
    k_stats<<<statsb, 192, 0, stream>>>(P, stats + l * 192);
    k_bnparams<<<1, 96, 0, stream>>>(stats + l * 192, gamma + l * 96, beta + l * 96,
                                     prm + l * 192);
    hin = P;  // next GEMM reads raw agg and applies BN+ReLU on load
  }

  k_pool<<<nb, 96, 0, stream>>>(P, prm + 3 * 192, batch, pool);
  k_gcount<<<nb, 256, 0, stream>>>(batch, gcnt);
  k_out<<<(N_GRAPHS * 96 + 255) / 256, 256, 0, stream>>>(pool, gcnt, out);
}

// Round 2
// 838.514 us; speedup vs baseline: 1.4838x; 1.4838x over previous
//
#include <hip/hip_runtime.h>
#include <hip/hip_bf16.h>

#define N_NODES 50000
#define N_EDGES 800000
#define DD 96
#define NLAYER 4
#define N_GRAPHS 256
#define BN_EPS 1e-5f

// ---------------- workspace layout (units: 4-byte elements) ----------------
enum : size_t {
  O_CNT    = 0,                        // int[N_NODES]
  O_STATS  = O_CNT + N_NODES,          // float[4*192]  (sum, sumsq per layer)
  O_POOL   = O_STATS + 4 * 192,        // float[N_GRAPHS*96]
  O_GCNT   = O_POOL + N_GRAPHS * DD,   // int[N_GRAPHS]
  ZERO_END = O_GCNT + N_GRAPHS,
  O_ROWPTR = ZERO_END,                 // int[N_NODES+1]
  O_DIS    = O_ROWPTR + N_NODES + 1,   // float[N_NODES]
  O_BSUMS  = O_DIS + N_NODES,          // int[256]
  O_EDG_RAW = O_BSUMS + 256,
  O_EDG    = (O_EDG_RAW + 1) & ~size_t(1),  // int2[N_EDGES] packed (src, weight-bits)
  O_B_RAW  = O_EDG + 2 * N_EDGES,
  O_B      = (O_B_RAW + 3) & ~size_t(3),  // float[N_NODES*96]  hw buffer
  O_P      = O_B + N_NODES * DD,          // float[N_NODES*96]  act/agg buffer
  WS_ELEMS = O_P + N_NODES * DD
};

__device__ __forceinline__ void atomAddF(float* p, float v) {
  unsafeAtomicAdd(p, v);  // native fp32 atomic add (no CAS loop)
}

// ---------------- CSR build ----------------
__global__ void k_count(const int* __restrict__ dst, int* __restrict__ cnt) {
  int e = blockIdx.x * blockDim.x + threadIdx.x;
  if (e < N_EDGES) atomicAdd(&cnt[dst[e]], 1);
}

__global__ void k_dis(const int* __restrict__ cnt, float* __restrict__ dis) {
  int n = blockIdx.x * blockDim.x + threadIdx.x;
  if (n < N_NODES) dis[n] = rsqrtf((float)(cnt[n] + 1));  // +1 self loop
}

__global__ void k_partials(const int* __restrict__ cnt, int* __restrict__ bsums) {
  __shared__ int s[256];
  int i = blockIdx.x * 256 + threadIdx.x;
  s[threadIdx.x] = (i < N_NODES) ? cnt[i] : 0;
  __syncthreads();
  for (int off = 128; off > 0; off >>= 1) {
    if (threadIdx.x < off) s[threadIdx.x] += s[threadIdx.x + off];
    __syncthreads();
  }
  if (threadIdx.x == 0) bsums[blockIdx.x] = s[0];
}

__global__ void k_scan_bsums(int* __restrict__ bsums, int nb, int* __restrict__ rowptr) {
  if (threadIdx.x == 0 && blockIdx.x == 0) {
    int run = 0;
    for (int b = 0; b < nb; ++b) { int t = bsums[b]; bsums[b] = run; run += t; }
    rowptr[N_NODES] = run;
  }
}

__global__ void k_scan_write(const int* __restrict__ cnt, const int* __restrict__ bsums,
                             int* __restrict__ rowptr) {
  __shared__ int s[256];
  int i = blockIdx.x * 256 + threadIdx.x;
  int v = (i < N_NODES) ? cnt[i] : 0;
  s[threadIdx.x] = v;
  __syncthreads();
  for (int off = 1; off < 256; off <<= 1) {
    int x = 0;
    if (threadIdx.x >= off) x = s[threadIdx.x - off];
    __syncthreads();
    s[threadIdx.x] += x;
    __syncthreads();
  }
  if (i < N_NODES) rowptr[i] = bsums[blockIdx.x] + s[threadIdx.x] - v;  // exclusive
}

__global__ void k_fill(const int* __restrict__ ei, const int* __restrict__ rowptr,
                       int* __restrict__ cursor, const float* __restrict__ dis,
                       int2* __restrict__ edg) {
  int e = blockIdx.x * blockDim.x + threadIdx.x;
  if (e >= N_EDGES) return;
  int s = ei[e];            // src
  int d = ei[N_EDGES + e];  // dst
  int pos = rowptr[d] + atomicAdd(&cursor[d], 1);
  edg[pos] = make_int2(s, __float_as_int(dis[s] * dis[d]));
}

// ---------------- GEMM: Y = act(X) @ W; act = BN(stats)+ReLU (identity if stats==null) ----
__global__ __launch_bounds__(192) void k_gemm(const float* __restrict__ X,
                                              const float* __restrict__ Wg,
                                              const float* __restrict__ stats,
                                              const float* __restrict__ gamma,
                                              const float* __restrict__ beta,
                                              float* __restrict__ Y) {
  __shared__ float Ws[96 * 96];
  __shared__ float Hs[48][100];
  __shared__ float sA[96], sC[96];
  const int tid = threadIdx.x;
  const int fg = tid % 24;
  const int rg = tid / 24;
  const int row0 = blockIdx.x * 48;

  for (int i = tid; i < 96 * 96; i += 192) Ws[i] = Wg[i];
  if (tid < 96) {
    if (stats) {
      float mu = stats[tid] * (1.f / N_NODES);
      float var = fmaxf(stats[96 + tid] * (1.f / N_NODES) - mu * mu, 0.f);
      float a = gamma[tid] * rsqrtf(var + BN_EPS);
      sA[tid] = a;
      sC[tid] = beta[tid] - mu * a;
    } else {
      sA[tid] = 1.f;
      sC[tid] = 0.f;
    }
  }
  __syncthreads();
  const bool bn = (stats != nullptr);
  for (int i = tid; i < 48 * 96; i += 192) {
    int r = i / 96, c = i - r * 96;
    int gr = row0 + r;
    float v = (gr < N_NODES) ? X[gr * 96 + c] : 0.f;
    if (bn) v = fmaxf(v * sA[c] + sC[c], 0.f);
    Hs[r][c] = v;
  }
  __syncthreads();

  float4 acc[6];
#pragma unroll
  for (int j = 0; j < 6; ++j) acc[j] = make_float4(0.f, 0.f, 0.f, 0.f);
  const int f4 = fg * 4;
  for (int k4 = 0; k4 < 96; k4 += 4) {
    float4 w0 = *(const float4*)&Ws[(k4 + 0) * 96 + f4];
    float4 w1 = *(const float4*)&Ws[(k4 + 1) * 96 + f4];
    float4 w2 = *(const float4*)&Ws[(k4 + 2) * 96 + f4];
    float4 w3 = *(const float4*)&Ws[(k4 + 3) * 96 + f4];
#pragma unroll
    for (int j = 0; j < 6; ++j) {
      const float4 h = *(const float4*)&Hs[rg + j * 8][k4];
      acc[j].x += h.x * w0.x + h.y * w1.x + h.z * w2.x + h.w * w3.x;
      acc[j].y += h.x * w0.y + h.y * w1.y + h.z * w2.y + h.w * w3.y;
      acc[j].z += h.x * w0.z + h.y * w1.z + h.z * w2.z + h.w * w3.z;
      acc[j].w += h.x * w0.w + h.y * w1.w + h.z * w2.w + h.w * w3.w;
    }
  }
#pragma unroll
  for (int j = 0; j < 6; ++j) {
    int r = row0 + rg + j * 8;
    if (r < N_NODES) *(float4*)&Y[r * 96 + f4] = acc[j];
  }
}

// ---------------- fused aggregation + BN-stats ----------------
// thread = (chain, quad); chain handles 4 consecutive nodes; float4 everywhere.
#define NPC 4  // nodes per chain
__global__ __launch_bounds__(192) void k_gather(const float* __restrict__ hw,
                                                const int* __restrict__ rowptr,
                                                const int2* __restrict__ edg,
                                                const float* __restrict__ dis,
                                                float* __restrict__ agg,
                                                float* __restrict__ stats) {
  __shared__ float s_red[192];
  const int tid = threadIdx.x;
  const int chain = blockIdx.x * 8 + tid / 24;
  const int q4 = (tid % 24) * 4;
  float ssum[4] = {0.f, 0.f, 0.f, 0.f};
  float ssq[4] = {0.f, 0.f, 0.f, 0.f};

#pragma unroll
  for (int k = 0; k < NPC; ++k) {
    int n = chain * NPC + k;
    if (n >= N_NODES) break;
    float dn = dis[n];
    float4 acc = *(const float4*)&hw[n * 96 + q4];
    float dn2 = dn * dn;
    acc.x *= dn2; acc.y *= dn2; acc.z *= dn2; acc.w *= dn2;
    int s = rowptr[n], e = rowptr[n + 1];
    for (int j = s; j < e; ++j) {
      int2 ed = edg[j];
      float w = __int_as_float(ed.y);
      const float4 v = *(const float4*)&hw[ed.x * 96 + q4];
      acc.x = fmaf(w, v.x, acc.x);
      acc.y = fmaf(w, v.y, acc.y);
      acc.z = fmaf(w, v.z, acc.z);
      acc.w = fmaf(w, v.w, acc.w);
    }
    *(float4*)&agg[n * 96 + q4] = acc;
    ssum[0] += acc.x; ssum[1] += acc.y; ssum[2] += acc.z; ssum[3] += acc.w;
    ssq[0] += acc.x * acc.x; ssq[1] += acc.y * acc.y;
    ssq[2] += acc.z * acc.z; ssq[3] += acc.w * acc.w;
  }

  // block reduce: 8 chains contribute to each channel
  if (tid < 192) s_red[tid] = 0.f;
  __syncthreads();
#pragma unroll
  for (int i = 0; i < 4; ++i) atomAddF(&s_red[q4 + i], ssum[i]);
#pragma unroll
  for (int i = 0; i < 4; ++i) atomAddF(&s_red[96 + q4 + i], ssq[i]);
  __syncthreads();
  if (tid < 192) atomAddF(&stats[tid], s_red[tid]);
}

// ---------------- pooling: final BN+ReLU + segment-sum over sorted batch ----------------
__global__ __launch_bounds__(192) void k_pool(const float* __restrict__ h,
                                              const float* __restrict__ stats,
                                              const float* __restrict__ gamma,
                                              const float* __restrict__ beta,
                                              const int* __restrict__ batch,
                                              float* __restrict__ pool) {
  __shared__ float sA[96], sC[96];
  const int tid = threadIdx.x;
  if (tid < 96) {
    float mu = stats[tid] * (1.f / N_NODES);
    float var = fmaxf(stats[96 + tid] * (1.f / N_NODES) - mu * mu, 0.f);
    float a = gamma[tid] * rsqrtf(var + BN_EPS);
    sA[tid] = a;
    sC[tid] = beta[tid] - mu * a;
  }
  __syncthreads();
  const int chain = blockIdx.x * 8 + tid / 24;
  const int q4 = (tid % 24) * 4;
  int n0 = chain * 32;
  if (n0 >= N_NODES) return;
  int n1 = min(n0 + 32, N_NODES);
  float A0 = sA[q4], A1 = sA[q4 + 1], A2 = sA[q4 + 2], A3 = sA[q4 + 3];
  float C0 = sC[q4], C1 = sC[q4 + 1], C2 = sC[q4 + 2], C3 = sC[q4 + 3];
  int cur = batch[n0];
  float4 acc = make_float4(0.f, 0.f, 0.f, 0.f);
  for (int n = n0; n < n1; ++n) {
    int g = batch[n];
    if (g != cur) {
      float* p = &pool[cur * 96 + q4];
      atomAddF(p, acc.x); atomAddF(p + 1, acc.y);
      atomAddF(p + 2, acc.z); atomAddF(p + 3, acc.w);
      acc = make_float4(0.f, 0.f, 0.f, 0.f);
      cur = g;
    }
    const float4 v = *(const float4*)&h[n * 96 + q4];
    acc.x += fmaxf(v.x * A0 + C0, 0.f);
    acc.y += fmaxf(v.y * A1 + C1, 0.f);
    acc.z += fmaxf(v.z * A2 + C2, 0.f);
    acc.w += fmaxf(v.w * A3 + C3, 0.f);
  }
  float* p = &pool[cur * 96 + q4];
  atomAddF(p, acc.x); atomAddF(p + 1, acc.y);
  atomAddF(p + 2, acc.z); atomAddF(p + 3, acc.w);
}

__global__ void k_gcount(const int* __restrict__ batch, int* __restrict__ gcnt) {
  int n = blockIdx.x * blockDim.x + threadIdx.x;
  if (n < N_NODES) atomicAdd(&gcnt[batch[n]], 1);
}

__global__ void k_out(const float* __restrict__ pool, const int* __restrict__ gcnt,
                      float* __restrict__ out) {
  int t = blockIdx.x * blockDim.x + threadIdx.x;
  if (t >= N_GRAPHS * 96) return;
  int g = t / 96;
  int c = gcnt[g];
  if (c < 1) c = 1;
  out[t] = pool[t] / (float)c;
}

extern "C" void kernel_launch(void* const* d_in, const int* in_sizes, int n_in,
                              void* d_out, int out_size, void* d_ws, size_t ws_size,
                              hipStream_t stream) {
  const float* x     = (const float*)d_in[0];
  const int*   ei    = (const int*)d_in[1];   // [2, E]: src row then dst row
  const int*   batch = (const int*)d_in[2];
  const float* W     = (const float*)d_in[3]; // [4,96,96]
  // d_in[4] = b : cancels exactly through BatchNorm, unused
  const float* gamma = (const float*)d_in[5]; // [4,96]
  const float* beta  = (const float*)d_in[6];
  float* out = (float*)d_out;

  float* ws = (float*)d_ws;
  int*   cnt    = (int*)(ws + O_CNT);
  float* stats  = ws + O_STATS;
  float* pool   = ws + O_POOL;
  int*   gcnt   = (int*)(ws + O_GCNT);
  int*   rowptr = (int*)(ws + O_ROWPTR);
  float* dis    = ws + O_DIS;
  int*   bsums  = (int*)(ws + O_BSUMS);
  int2*  edg    = (int2*)(ws + O_EDG);
  float* B      = ws + O_B;  // hw
  float* P      = ws + O_P;  // act / agg

  hipMemsetAsync(d_ws, 0, ZERO_END * sizeof(float), stream);

  const int eb = (N_EDGES + 255) / 256;
  const int nb = (N_NODES + 255) / 256;  // 196
  k_count<<<eb, 256, 0, stream>>>(ei + N_EDGES, cnt);
  k_dis<<<nb, 256, 0, stream>>>(cnt, dis);
  k_partials<<<nb, 256, 0, stream>>>(cnt, bsums);
  k_scan_bsums<<<1, 64, 0, stream>>>(bsums, nb, rowptr);
  k_scan_write<<<nb, 256, 0, stream>>>(cnt, bsums, rowptr);
  hipMemsetAsync(cnt, 0, N_NODES * sizeof(int), stream);  // reuse as fill cursors
  k_fill<<<eb, 256, 0, stream>>>(ei, rowptr, cnt, dis, edg);

  const int gemmb = (N_NODES + 47) / 48;                       // 1042
  const int chains = (N_NODES + NPC - 1) / NPC;                // 12500
  const int gatherb = (chains + 7) / 8;                        // 1563

  const float* hin = x;
  for (int l = 0; l < NLAYER; ++l) {
    const float* st = (l == 0) ? nullptr : (stats + (l - 1) * 192);
    const float* ga = (l == 0) ? nullptr : (gamma + (l - 1) * 96);
    const float* be = (l == 0) ? nullptr : (beta + (l - 1) * 96);
    k_gemm<<<gemmb, 192, 0, stream>>>(hin, W + l * 96 * 96, st, ga, be, B);
    k_gather<<<gatherb, 192, 0, stream>>>(B, rowptr, edg, dis, P, stats + l * 192);
    hin = P;
  }

  const int poolb = ((N_NODES + 31) / 32 + 7) / 8;  // 196
  k_pool<<<poolb, 192, 0, stream>>>(P, stats + 3 * 192, gamma + 3 * 96, beta + 3 * 96,
                                    batch, pool);
  k_gcount<<<nb, 256, 0, stream>>>(batch, gcnt);
  k_out<<<(N_GRAPHS * 96 + 255) / 256, 256, 0, stream>>>(pool, gcnt, out);
}

// Round 3
// 786.943 us; speedup vs baseline: 1.5810x; 1.0655x over previous
//
#include <hip/hip_runtime.h>
#include <hip/hip_bf16.h>

#define N_NODES 50000
#define N_EDGES 800000
#define DD 96
#define NLAYER 4
#define N_GRAPHS 256
#define BN_EPS 1e-5f

// ---------------- workspace layout (units: 4-byte elements) ----------------
enum : size_t {
  O_CNT    = 0,                        // int[N_NODES]
  O_STATS  = O_CNT + N_NODES,          // float[4*192]  (sum, sumsq per layer)
  O_POOL   = O_STATS + 4 * 192,        // float[N_GRAPHS*96]
  O_GCNT   = O_POOL + N_GRAPHS * DD,   // int[N_GRAPHS]
  ZERO_END = O_GCNT + N_GRAPHS,
  O_ROWPTR = ZERO_END,                 // int[N_NODES+1]
  O_DIS    = O_ROWPTR + N_NODES + 1,   // float[N_NODES]
  O_BSUMS  = O_DIS + N_NODES,          // int[256]
  O_EDG_RAW = O_BSUMS + 256,
  O_EDG    = (O_EDG_RAW + 1) & ~size_t(1),  // int2[N_EDGES] packed (src, weight-bits)
  O_B_RAW  = O_EDG + 2 * N_EDGES,
  O_B      = (O_B_RAW + 3) & ~size_t(3),  // float[N_NODES*96]  hw buffer
  O_P      = O_B + N_NODES * DD,          // float[N_NODES*96]  act/agg buffer
  WS_ELEMS = O_P + N_NODES * DD
};

__device__ __forceinline__ void atomAddF(float* p, float v) {
  unsafeAtomicAdd(p, v);  // native fp32 atomic add
}

// ---------------- CSR build ----------------
__global__ void k_count(const int* __restrict__ dst, int* __restrict__ cnt) {
  int e = blockIdx.x * blockDim.x + threadIdx.x;
  if (e < N_EDGES) atomicAdd(&cnt[dst[e]], 1);
}

__global__ void k_dis(const int* __restrict__ cnt, float* __restrict__ dis) {
  int n = blockIdx.x * blockDim.x + threadIdx.x;
  if (n < N_NODES) dis[n] = rsqrtf((float)(cnt[n] + 1));  // +1 self loop
}

__global__ void k_partials(const int* __restrict__ cnt, int* __restrict__ bsums) {
  __shared__ int s[256];
  int i = blockIdx.x * 256 + threadIdx.x;
  s[threadIdx.x] = (i < N_NODES) ? cnt[i] : 0;
  __syncthreads();
  for (int off = 128; off > 0; off >>= 1) {
    if (threadIdx.x < off) s[threadIdx.x] += s[threadIdx.x + off];
    __syncthreads();
  }
  if (threadIdx.x == 0) bsums[blockIdx.x] = s[0];
}

__global__ void k_scan_bsums(int* __restrict__ bsums, int nb, int* __restrict__ rowptr) {
  if (threadIdx.x == 0 && blockIdx.x == 0) {
    int run = 0;
    for (int b = 0; b < nb; ++b) { int t = bsums[b]; bsums[b] = run; run += t; }
    rowptr[N_NODES] = run;
  }
}

__global__ void k_scan_write(const int* __restrict__ cnt, const int* __restrict__ bsums,
                             int* __restrict__ rowptr) {
  __shared__ int s[256];
  int i = blockIdx.x * 256 + threadIdx.x;
  int v = (i < N_NODES) ? cnt[i] : 0;
  s[threadIdx.x] = v;
  __syncthreads();
  for (int off = 1; off < 256; off <<= 1) {
    int x = 0;
    if (threadIdx.x >= off) x = s[threadIdx.x - off];
    __syncthreads();
    s[threadIdx.x] += x;
    __syncthreads();
  }
  if (i < N_NODES) rowptr[i] = bsums[blockIdx.x] + s[threadIdx.x] - v;  // exclusive
}

__global__ void k_fill(const int* __restrict__ ei, const int* __restrict__ rowptr,
                       int* __restrict__ cursor, const float* __restrict__ dis,
                       int2* __restrict__ edg) {
  int e = blockIdx.x * blockDim.x + threadIdx.x;
  if (e >= N_EDGES) return;
  int s = ei[e];            // src
  int d = ei[N_EDGES + e];  // dst
  int pos = rowptr[d] + atomicAdd(&cursor[d], 1);
  edg[pos] = make_int2(s, __float_as_int(dis[s] * dis[d]));
}

// ---------------- GEMM: Y = act(X) @ W; act = BN(stats)+ReLU (identity if stats==null) ----
__global__ __launch_bounds__(192) void k_gemm(const float* __restrict__ X,
                                              const float* __restrict__ Wg,
                                              const float* __restrict__ stats,
                                              const float* __restrict__ gamma,
                                              const float* __restrict__ beta,
                                              float* __restrict__ Y) {
  __shared__ float Ws[96 * 96];
  __shared__ float Hs[48][100];
  __shared__ float sA[96], sC[96];
  const int tid = threadIdx.x;
  const int fg = tid % 24;
  const int rg = tid / 24;
  const int row0 = blockIdx.x * 48;

  for (int i = tid; i < 96 * 24; i += 192)
    *(float4*)&Ws[i * 4] = *(const float4*)&Wg[i * 4];
  if (tid < 96) {
    if (stats) {
      float mu = stats[tid] * (1.f / N_NODES);
      float var = fmaxf(stats[96 + tid] * (1.f / N_NODES) - mu * mu, 0.f);
      float a = gamma[tid] * rsqrtf(var + BN_EPS);
      sA[tid] = a;
      sC[tid] = beta[tid] - mu * a;
    } else {
      sA[tid] = 1.f;
      sC[tid] = 0.f;
    }
  }
  __syncthreads();
  const bool bn = (stats != nullptr);
  for (int i = tid; i < 48 * 24; i += 192) {
    int r = i / 24, c4 = (i % 24) * 4;
    int gr = row0 + r;
    float4 v = (gr < N_NODES) ? *(const float4*)&X[gr * 96 + c4]
                              : make_float4(0.f, 0.f, 0.f, 0.f);
    if (bn) {
      v.x = fmaxf(v.x * sA[c4] + sC[c4], 0.f);
      v.y = fmaxf(v.y * sA[c4 + 1] + sC[c4 + 1], 0.f);
      v.z = fmaxf(v.z * sA[c4 + 2] + sC[c4 + 2], 0.f);
      v.w = fmaxf(v.w * sA[c4 + 3] + sC[c4 + 3], 0.f);
    }
    *(float4*)&Hs[r][c4] = v;
  }
  __syncthreads();

  float4 acc[6];
#pragma unroll
  for (int j = 0; j < 6; ++j) acc[j] = make_float4(0.f, 0.f, 0.f, 0.f);
  const int f4 = fg * 4;
  for (int k4 = 0; k4 < 96; k4 += 4) {
    float4 w0 = *(const float4*)&Ws[(k4 + 0) * 96 + f4];
    float4 w1 = *(const float4*)&Ws[(k4 + 1) * 96 + f4];
    float4 w2 = *(const float4*)&Ws[(k4 + 2) * 96 + f4];
    float4 w3 = *(const float4*)&Ws[(k4 + 3) * 96 + f4];
#pragma unroll
    for (int j = 0; j < 6; ++j) {
      const float4 h = *(const float4*)&Hs[rg + j * 8][k4];
      acc[j].x += h.x * w0.x + h.y * w1.x + h.z * w2.x + h.w * w3.x;
      acc[j].y += h.x * w0.y + h.y * w1.y + h.z * w2.y + h.w * w3.y;
      acc[j].z += h.x * w0.z + h.y * w1.z + h.z * w2.z + h.w * w3.z;
      acc[j].w += h.x * w0.w + h.y * w1.w + h.z * w2.w + h.w * w3.w;
    }
  }
#pragma unroll
  for (int j = 0; j < 6; ++j) {
    int r = row0 + rg + j * 8;
    if (r < N_NODES) *(float4*)&Y[r * 96 + f4] = acc[j];
  }
}

// ---------------- fused aggregation + BN-stats ----------------
// thread = (chain, quad). The chain's 4 nodes advance as 4 INDEPENDENT
// interleaved load streams (branchless) => 4x memory-level parallelism.
#define NPC 4
__global__ __launch_bounds__(192) void k_gather(const float* __restrict__ hw,
                                                const int* __restrict__ rowptr,
                                                const int2* __restrict__ edg,
                                                const float* __restrict__ dis,
                                                float* __restrict__ agg,
                                                float* __restrict__ stats) {
  __shared__ float s_red[192];
  const int tid = threadIdx.x;
  const int chain = blockIdx.x * 8 + tid / 24;
  const int q4 = (tid % 24) * 4;
  const int n0 = chain * NPC;

  int j[NPC], e[NPC];
  float4 a[NPC];
#pragma unroll
  for (int k = 0; k < NPC; ++k) {
    int n = n0 + k;
    bool valid = (n < N_NODES);
    int nc = valid ? n : (N_NODES - 1);
    j[k] = rowptr[nc];
    e[k] = valid ? rowptr[nc + 1] : j[k];  // empty range for padding nodes
    float dn = dis[nc];
    float4 h = *(const float4*)&hw[nc * 96 + q4];
    float s = dn * dn;
    a[k] = make_float4(h.x * s, h.y * s, h.z * s, h.w * s);
  }

  while ((j[0] < e[0]) | (j[1] < e[1]) | (j[2] < e[2]) | (j[3] < e[3])) {
    int2 ed[NPC];
    bool m[NPC];
#pragma unroll
    for (int k = 0; k < NPC; ++k) {
      m[k] = j[k] < e[k];
      int idx = j[k] < (N_EDGES - 1) ? j[k] : (N_EDGES - 1);
      ed[k] = edg[idx];  // unconditional: keeps the 4 streams branchless
    }
    float4 v[NPC];
#pragma unroll
    for (int k = 0; k < NPC; ++k) v[k] = *(const float4*)&hw[ed[k].x * 96 + q4];
#pragma unroll
    for (int k = 0; k < NPC; ++k) {
      float w = m[k] ? __int_as_float(ed[k].y) : 0.f;
      a[k].x = fmaf(w, v[k].x, a[k].x);
      a[k].y = fmaf(w, v[k].y, a[k].y);
      a[k].z = fmaf(w, v[k].z, a[k].z);
      a[k].w = fmaf(w, v[k].w, a[k].w);
      j[k] += m[k] ? 1 : 0;
    }
  }

  float ssum[4] = {0.f, 0.f, 0.f, 0.f};
  float ssq[4] = {0.f, 0.f, 0.f, 0.f};
#pragma unroll
  for (int k = 0; k < NPC; ++k) {
    int n = n0 + k;
    if (n < N_NODES) {
      *(float4*)&agg[n * 96 + q4] = a[k];
      ssum[0] += a[k].x; ssum[1] += a[k].y; ssum[2] += a[k].z; ssum[3] += a[k].w;
      ssq[0] += a[k].x * a[k].x; ssq[1] += a[k].y * a[k].y;
      ssq[2] += a[k].z * a[k].z; ssq[3] += a[k].w * a[k].w;
    }
  }

  s_red[tid] = 0.f;
  __syncthreads();
#pragma unroll
  for (int i = 0; i < 4; ++i) atomAddF(&s_red[q4 + i], ssum[i]);
#pragma unroll
  for (int i = 0; i < 4; ++i) atomAddF(&s_red[96 + q4 + i], ssq[i]);
  __syncthreads();
  if (tid < 192) atomAddF(&stats[tid], s_red[tid]);
}

// ---------------- pooling: final BN+ReLU + segment-sum over sorted batch ----------------
__global__ __launch_bounds__(192) void k_pool(const float* __restrict__ h,
                                              const float* __restrict__ stats,
                                              const float* __restrict__ gamma,
                                              const float* __restrict__ beta,
                                              const int* __restrict__ batch,
                                              float* __restrict__ pool) {
  __shared__ float sA[96], sC[96];
  const int tid = threadIdx.x;
  if (tid < 96) {
    float mu = stats[tid] * (1.f / N_NODES);
    float var = fmaxf(stats[96 + tid] * (1.f / N_NODES) - mu * mu, 0.f);
    float a = gamma[tid] * rsqrtf(var + BN_EPS);
    sA[tid] = a;
    sC[tid] = beta[tid] - mu * a;
  }
  __syncthreads();
  const int chain = blockIdx.x * 8 + tid / 24;
  const int q4 = (tid % 24) * 4;
  int n0 = chain * 32;
  if (n0 >= N_NODES) return;
  int n1 = min(n0 + 32, N_NODES);
  float A0 = sA[q4], A1 = sA[q4 + 1], A2 = sA[q4 + 2], A3 = sA[q4 + 3];
  float C0 = sC[q4], C1 = sC[q4 + 1], C2 = sC[q4 + 2], C3 = sC[q4 + 3];
  int cur = batch[n0];
  float4 acc = make_float4(0.f, 0.f, 0.f, 0.f);
  for (int n = n0; n < n1; ++n) {
    int g = batch[n];
    if (g != cur) {
      float* p = &pool[cur * 96 + q4];
      atomAddF(p, acc.x); atomAddF(p + 1, acc.y);
      atomAddF(p + 2, acc.z); atomAddF(p + 3, acc.w);
      acc = make_float4(0.f, 0.f, 0.f, 0.f);
      cur = g;
    }
    const float4 v = *(const float4*)&h[n * 96 + q4];
    acc.x += fmaxf(v.x * A0 + C0, 0.f);
    acc.y += fmaxf(v.y * A1 + C1, 0.f);
    acc.z += fmaxf(v.z * A2 + C2, 0.f);
    acc.w += fmaxf(v.w * A3 + C3, 0.f);
  }
  float* p = &pool[cur * 96 + q4];
  atomAddF(p, acc.x); atomAddF(p + 1, acc.y);
  atomAddF(p + 2, acc.z); atomAddF(p + 3, acc.w);
}

__global__ void k_gcount(const int* __restrict__ batch, int* __restrict__ gcnt) {
  int n = blockIdx.x * blockDim.x + threadIdx.x;
  if (n < N_NODES) atomicAdd(&gcnt[batch[n]], 1);
}

__global__ void k_out(const float* __restrict__ pool, const int* __restrict__ gcnt,
                      float* __restrict__ out) {
  int t = blockIdx.x * blockDim.x + threadIdx.x;
  if (t >= N_GRAPHS * 96) return;
  int g = t / 96;
  int c = gcnt[g];
  if (c < 1) c = 1;
  out[t] = pool[t] / (float)c;
}

extern "C" void kernel_launch(void* const* d_in, const int* in_sizes, int n_in,
                              void* d_out, int out_size, void* d_ws, size_t ws_size,
                              hipStream_t stream) {
  const float* x     = (const float*)d_in[0];
  const int*   ei    = (const int*)d_in[1];   // [2, E]: src row then dst row
  const int*   batch = (const int*)d_in[2];
  const float* W     = (const float*)d_in[3]; // [4,96,96]
  // d_in[4] = b : cancels exactly through BatchNorm, unused
  const float* gamma = (const float*)d_in[5]; // [4,96]
  const float* beta  = (const float*)d_in[6];
  float* out = (float*)d_out;

  float* ws = (float*)d_ws;
  int*   cnt    = (int*)(ws + O_CNT);
  float* stats  = ws + O_STATS;
  float* pool   = ws + O_POOL;
  int*   gcnt   = (int*)(ws + O_GCNT);
  int*   rowptr = (int*)(ws + O_ROWPTR);
  float* dis    = ws + O_DIS;
  int*   bsums  = (int*)(ws + O_BSUMS);
  int2*  edg    = (int2*)(ws + O_EDG);
  float* B      = ws + O_B;  // hw
  float* P      = ws + O_P;  // act / agg

  hipMemsetAsync(d_ws, 0, ZERO_END * sizeof(float), stream);

  const int eb = (N_EDGES + 255) / 256;
  const int nb = (N_NODES + 255) / 256;  // 196
  k_count<<<eb, 256, 0, stream>>>(ei + N_EDGES, cnt);
  k_dis<<<nb, 256, 0, stream>>>(cnt, dis);
  k_partials<<<nb, 256, 0, stream>>>(cnt, bsums);
  k_scan_bsums<<<1, 64, 0, stream>>>(bsums, nb, rowptr);
  k_scan_write<<<nb, 256, 0, stream>>>(cnt, bsums, rowptr);
  hipMemsetAsync(cnt, 0, N_NODES * sizeof(int), stream);  // reuse as fill cursors
  k_fill<<<eb, 256, 0, stream>>>(ei, rowptr, cnt, dis, edg);

  const int gemmb = (N_NODES + 47) / 48;                       // 1042
  const int chains = (N_NODES + NPC - 1) / NPC;                // 12500
  const int gatherb = (chains + 7) / 8;                        // 1563

  const float* hin = x;
  for (int l = 0; l < NLAYER; ++l) {
    const float* st = (l == 0) ? nullptr : (stats + (l - 1) * 192);
    const float* ga = (l == 0) ? nullptr : (gamma + (l - 1) * 96);
    const float* be = (l == 0) ? nullptr : (beta + (l - 1) * 96);
    k_gemm<<<gemmb, 192, 0, stream>>>(hin, W + l * 96 * 96, st, ga, be, B);
    k_gather<<<gatherb, 192, 0, stream>>>(B, rowptr, edg, dis, P, stats + l * 192);
    hin = P;
  }

  const int poolb = ((N_NODES + 31) / 32 + 7) / 8;  // 196
  k_pool<<<poolb, 192, 0, stream>>>(P, stats + 3 * 192, gamma + 3 * 96, beta + 3 * 96,
                                    batch, pool);
  k_gcount<<<nb, 256, 0, stream>>>(batch, gcnt);
  k_out<<<(N_GRAPHS * 96 + 255) / 256, 256, 0, stream>>>(pool, gcnt, out);
}